// Round 1
// baseline (1362.352 us; speedup 1.0000x reference)
//
#include <hip/hip_runtime.h>

// Fused transformer block, fp32, one thread per (sequence,row).
// t=8 rows/seq live in 8 consecutive lanes of one wave -> wave-synchronous
// K/V exchange via LDS, no __syncthreads needed.
// Weights are read with wave-uniform indices from __restrict__ const pointers
// so the compiler can scalarize them (s_load + v_fmac with SGPR operand).

#define SEQ_PB 32
#define THREADS 256
#define KV_STRIDE 260   // 4*8*8 = 256 floats per seq + 4 pad -> bank spread, 16B aligned

__global__ __launch_bounds__(THREADS)
void block_fused(const float* __restrict__ X,
                 const float* __restrict__ Wattn,   // (4,32,24) [h][c][d], d: k=0..7,q=8..15,v=16..23
                 const float* __restrict__ Wproj,   // (32,32)  [cin][cout]
                 const float* __restrict__ Wff1,    // (32,128) [c][j]
                 const float* __restrict__ Wff2,    // (128,32) [j][c]
                 float* __restrict__ Out,
                 int nseq)
{
    __shared__ float sK[SEQ_PB * KV_STRIDE];
    __shared__ float sV[SEQ_PB * KV_STRIDE];

    const int tid = threadIdx.x;
    const int s_local = tid >> 3;          // 0..31
    const int t = tid & 7;                 // row within sequence
    const int seq = blockIdx.x * SEQ_PB + s_local;
    if (seq >= nseq) return;               // no barriers in kernel -> safe

    const float scale = 0.17677669529663687f;  // 32^-0.5 (full embed dim, per reference)

    // ---- load my row of X (32 floats, 8x float4) ----
    const float* xrow = X + (size_t)seq * 256 + (size_t)t * 32;
    float x[32];
    #pragma unroll
    for (int i = 0; i < 8; ++i) {
        float4 v4 = reinterpret_cast<const float4*>(xrow)[i];
        x[4*i+0] = v4.x; x[4*i+1] = v4.y; x[4*i+2] = v4.z; x[4*i+3] = v4.w;
    }

    // x2 accumulates: x + attn @ Wproj  (proj folded into the head loop)
    float x2[32];
    #pragma unroll
    for (int c = 0; c < 32; ++c) x2[c] = x[c];

    float* kbase = &sK[s_local * KV_STRIDE];
    float* vbase = &sV[s_local * KV_STRIDE];

    // ---- per-head: QKV -> LDS(k,v) -> scores -> softmax -> attn -> +proj ----
    #pragma unroll 1
    for (int h = 0; h < 4; ++h) {
        // qkv for my row, this head: acc[0..7]=k, [8..15]=q, [16..23]=v
        float acc[24];
        #pragma unroll
        for (int d = 0; d < 24; ++d) acc[d] = 0.0f;
        const float* wa = Wattn + h * 768;   // (h*32+c)*24 + d
        #pragma unroll
        for (int c = 0; c < 32; ++c) {
            float xc = x[c];
            #pragma unroll
            for (int d = 0; d < 24; ++d)
                acc[d] = fmaf(xc, wa[c * 24 + d], acc[d]);
        }

        // stash k, v for my row into LDS (read back wave-synchronously below)
        float* kb = kbase + h * 64 + t * 8;
        float* vb = vbase + h * 64 + t * 8;
        #pragma unroll
        for (int d = 0; d < 8; ++d) { kb[d] = acc[d]; vb[d] = acc[16 + d]; }

        // scores over all 8 key rows (causal mask via big negative)
        float sc[8];
        float m = -1e30f;
        #pragma unroll
        for (int j = 0; j < 8; ++j) {
            const float* kr = kbase + h * 64 + j * 8;
            float dot = 0.0f;
            #pragma unroll
            for (int d = 0; d < 8; ++d)
                dot = fmaf(acc[8 + d], kr[d], dot);
            sc[j] = (j <= t) ? dot * scale : -1e30f;
            m = fmaxf(m, sc[j]);
        }
        float e[8];
        float sum = 0.0f;
        #pragma unroll
        for (int j = 0; j < 8; ++j) { e[j] = __expf(sc[j] - m); sum += e[j]; }
        float inv = 1.0f / sum;

        // attn_h[d] = sum_j w_j * v_j[d]
        float ad[8];
        #pragma unroll
        for (int d = 0; d < 8; ++d) ad[d] = 0.0f;
        #pragma unroll
        for (int j = 0; j < 8; ++j) {
            float w = e[j];
            const float* vr = vbase + h * 64 + j * 8;
            #pragma unroll
            for (int d = 0; d < 8; ++d)
                ad[d] = fmaf(w, vr[d], ad[d]);
        }

        // fold proj: x2[c] += attn_h[d] * Wproj[h*8+d][c]
        #pragma unroll
        for (int d = 0; d < 8; ++d) {
            float adv = ad[d] * inv;
            const float* wp = Wproj + (h * 8 + d) * 32;
            #pragma unroll
            for (int c = 0; c < 32; ++c)
                x2[c] = fmaf(adv, wp[c], x2[c]);
        }
    }

    // ---- FF: out = x2 + relu(x2 @ Wff1) @ Wff2, hidden in chunks of 8 ----
    float out[32];
    #pragma unroll
    for (int c = 0; c < 32; ++c) out[c] = x2[c];

    #pragma unroll 1
    for (int jb = 0; jb < 16; ++jb) {
        float hacc[8];
        #pragma unroll
        for (int j = 0; j < 8; ++j) hacc[j] = 0.0f;
        #pragma unroll
        for (int c = 0; c < 32; ++c) {
            float xc = x2[c];
            const float* w1 = Wff1 + c * 128 + jb * 8;
            #pragma unroll
            for (int j = 0; j < 8; ++j)
                hacc[j] = fmaf(xc, w1[j], hacc[j]);
        }
        #pragma unroll
        for (int j = 0; j < 8; ++j) {
            float hj = fmaxf(hacc[j], 0.0f);
            const float* w2 = Wff2 + (jb * 8 + j) * 32;
            #pragma unroll
            for (int c = 0; c < 32; ++c)
                out[c] = fmaf(hj, w2[c], out[c]);
        }
    }

    // ---- store ----
    float* orow = Out + (size_t)seq * 256 + (size_t)t * 32;
    #pragma unroll
    for (int i = 0; i < 8; ++i) {
        float4 v4 = make_float4(out[4*i+0], out[4*i+1], out[4*i+2], out[4*i+3]);
        reinterpret_cast<float4*>(orow)[i] = v4;
    }
}

extern "C" void kernel_launch(void* const* d_in, const int* in_sizes, int n_in,
                              void* d_out, int out_size, void* d_ws, size_t ws_size,
                              hipStream_t stream) {
    (void)n_in; (void)out_size; (void)d_ws; (void)ws_size;
    const float* X     = (const float*)d_in[0];
    const float* Wattn = (const float*)d_in[1];
    const float* Wproj = (const float*)d_in[2];
    const float* Wff1  = (const float*)d_in[3];
    const float* Wff2  = (const float*)d_in[4];
    float* Out = (float*)d_out;

    const int nseq = in_sizes[0] / 256;            // (b, 8, 32)
    const int blocks = (nseq + SEQ_PB - 1) / SEQ_PB;
    block_fused<<<dim3(blocks), dim3(THREADS), 0, stream>>>(
        X, Wattn, Wproj, Wff1, Wff2, Out, nseq);
}